// Round 1
// 425.507 us; speedup vs baseline: 1.0878x; 1.0878x over previous
//
#include <hip/hip_runtime.h>
#include <hip/hip_bf16.h>

#define N_NODES 8192
#define N_EDGES 262144
// F_IN=512, H1=256, H2=128 (x2 fused = 256), H3=64, OUT6=6

typedef __attribute__((ext_vector_type(8))) short short8;
typedef __attribute__((ext_vector_type(4))) float f32x4;

__device__ __forceinline__ unsigned short f2bf(float f) {
    unsigned int u = __float_as_uint(f);
    u = (u + 0x7fffu + ((u >> 16) & 1u)) >> 16;  // RNE
    return (unsigned short)u;
}
__device__ __forceinline__ float bf2f(unsigned short h) {
    return __uint_as_float((unsigned int)h << 16);
}

// ---------------- CSR build (counting sort by row) ----------------
__global__ void k_hist(const int* __restrict__ rows, int* __restrict__ counts) {
    int e = blockIdx.x * 256 + threadIdx.x;
    if (e < N_EDGES) atomicAdd(&counts[rows[e]], 1);
}

__global__ void k_scan(const int* __restrict__ counts, int* __restrict__ offs) {
    __shared__ int part[1024];
    int t = threadIdx.x;
    int base = t * 8;
    int loc[8];
    int s = 0;
#pragma unroll
    for (int i = 0; i < 8; i++) { loc[i] = s; s += counts[base + i]; }
    part[t] = s;
    __syncthreads();
    for (int off = 1; off < 1024; off <<= 1) {
        int v = (t >= off) ? part[t - off] : 0;
        __syncthreads();
        part[t] += v;
        __syncthreads();
    }
    int prev = (t == 0) ? 0 : part[t - 1];
#pragma unroll
    for (int i = 0; i < 8; i++) offs[base + i] = prev + loc[i];
    if (t == 1023) offs[N_NODES] = part[1023];
}

__global__ void k_scatter(const int* __restrict__ rows, const int* __restrict__ colsIn,
                          const float* __restrict__ valsIn, const int* __restrict__ offs,
                          int* __restrict__ cursor, int* __restrict__ colsOut,
                          float* __restrict__ valsOut) {
    int e = blockIdx.x * 256 + threadIdx.x;
    if (e >= N_EDGES) return;
    int r = rows[e];
    int p = atomicAdd(&cursor[r], 1);
    int idx = offs[r] + p;
    colsOut[idx] = colsIn[e];
    valsOut[idx] = valsIn[e];
}

// ---------------- fp32 -> bf16 converts ----------------
// x [8192,512] -> bf16, vectorized 4/thread
__global__ void k_conv_x(const float* __restrict__ in, ushort* __restrict__ out) {
    int i = blockIdx.x * 256 + threadIdx.x;  // over 4194304/4 = 1048576
    float4 v = ((const float4*)in)[i];
    ushort4 o = make_ushort4(f2bf(v.x), f2bf(v.y), f2bf(v.z), f2bf(v.w));
    ((ushort4*)out)[i] = o;
}

// W1 [512,256] fp32 -> W1t [256,512] bf16 (transposed for MFMA B-operand)
__global__ void k_w1t(const float* __restrict__ W, ushort* __restrict__ Wt) {
    int i = blockIdx.x * 256 + threadIdx.x;  // over 131072
    int k = i >> 8, n = i & 255;
    Wt[n * 512 + k] = f2bf(W[i]);
}

// W23t [256,256] bf16: W23t[n][k] = (n<128) ? W2[k][n] : W3[k][n-128]
__global__ void k_w23t(const float* __restrict__ W2, const float* __restrict__ W3,
                       ushort* __restrict__ Wt) {
    int i = blockIdx.x * 256 + threadIdx.x;  // over 65536, i = n*256 + k
    int n = i >> 8, k = i & 255;
    float v = (n < 128) ? W2[k * 128 + n] : W3[k * 128 + (n - 128)];
    Wt[i] = f2bf(v);
}

// ---------------- bf16 MFMA GEMM: C[M,ldc] = A[M,K] @ Bt[N,K]^T, bf16 out ----------------
// block = 256 thr = 4 waves, block tile 128x128, wave tile 64x64.
// Fragments straight from global (A streamed, Bt tiny/L2) with 2-deep register prefetch.
__global__ __launch_bounds__(256) void k_gemm_mfma(const ushort* __restrict__ A,
                                                   const ushort* __restrict__ Bt,
                                                   ushort* __restrict__ C,
                                                   int K, int ldc) {
    int t = threadIdx.x;
    int lane = t & 63;
    int w = t >> 6;
    int I = blockIdx.y * 128 + (w >> 1) * 64;
    int J = blockIdx.x * 128 + (w & 1) * 64;
    int r = lane & 15;
    int koff = (lane >> 4) * 8;
    const ushort* Ab = A + (size_t)(I + r) * K + koff;
    const ushort* Bb = Bt + (size_t)(J + r) * K + koff;
    size_t rs = (size_t)16 * K;

    short8 a0[4], b0[4], a1[4], b1[4];
#pragma unroll
    for (int m = 0; m < 4; m++) {
        a0[m] = *(const short8*)(Ab + m * rs);
        b0[m] = *(const short8*)(Bb + m * rs);
    }
    f32x4 acc[4][4];
#pragma unroll
    for (int m = 0; m < 4; m++)
#pragma unroll
        for (int n = 0; n < 4; n++) acc[m][n] = (f32x4){0.f, 0.f, 0.f, 0.f};

    int nk = K >> 5;  // K=512 -> 16, K=256 -> 8 (always even)
    for (int kt = 0; kt < nk; kt += 2) {
        int o1 = (kt + 1) << 5;
#pragma unroll
        for (int m = 0; m < 4; m++) {
            a1[m] = *(const short8*)(Ab + m * rs + o1);
            b1[m] = *(const short8*)(Bb + m * rs + o1);
        }
#pragma unroll
        for (int m = 0; m < 4; m++)
#pragma unroll
            for (int n = 0; n < 4; n++)
                acc[m][n] = __builtin_amdgcn_mfma_f32_16x16x32_bf16(a0[m], b0[n], acc[m][n], 0, 0, 0);
        if (kt + 2 < nk) {
            int o2 = (kt + 2) << 5;
#pragma unroll
            for (int m = 0; m < 4; m++) {
                a0[m] = *(const short8*)(Ab + m * rs + o2);
                b0[m] = *(const short8*)(Bb + m * rs + o2);
            }
        }
#pragma unroll
        for (int m = 0; m < 4; m++)
#pragma unroll
            for (int n = 0; n < 4; n++)
                acc[m][n] = __builtin_amdgcn_mfma_f32_16x16x32_bf16(a1[m], b1[n], acc[m][n], 0, 0, 0);
    }

    // C/D layout: col = lane&15, row = (lane>>4)*4 + reg   [m89-verified]
    int crow = (lane >> 4) * 4;
    int ccol = lane & 15;
#pragma unroll
    for (int m = 0; m < 4; m++)
#pragma unroll
        for (int rg = 0; rg < 4; rg++) {
            size_t row = (size_t)(I + m * 16 + crow + rg);
#pragma unroll
            for (int n = 0; n < 4; n++)
                C[row * ldc + J + n * 16 + ccol] = f2bf(acc[m][n][rg]);
        }
}

// ---------------- SpMM (CSR), D=256, bf16 in, fp32 accumulate ----------------
// outh != null -> bf16 out (with optional relu); else fp32 out.
__global__ __launch_bounds__(256) void k_spmm_h(const int* __restrict__ offs,
                                                const int* __restrict__ cols,
                                                const float* __restrict__ vals,
                                                const ushort* __restrict__ in,
                                                ushort* __restrict__ outh,
                                                float* __restrict__ outf, int relu) {
    const int row = blockIdx.x;
    const int d = threadIdx.x;
    int s = offs[row], e = offs[row + 1];
    float acc = 0.f;
    __shared__ int sc[256];
    __shared__ float sv[256];
    for (int base = s; base < e; base += 256) {
        int n = e - base;
        if (n > 256) n = 256;
        if (d < n) { sc[d] = cols[base + d]; sv[d] = vals[base + d]; }
        __syncthreads();
        for (int i = 0; i < n; i++)
            acc += sv[i] * bf2f(in[(size_t)sc[i] * 256 + d]);
        __syncthreads();
    }
    if (relu) acc = fmaxf(acc, 0.f);
    if (outh) outh[(size_t)row * 256 + d] = f2bf(acc);
    else outf[(size_t)row * 256 + d] = acc;
}

// ---------------- fused dense: [mu;logvar] = Mb(view [16384,128]) @ dense_W + b ----------------
// Mb row r = [mu0_r (128) | logvar0_r (128)] -> interleaved view row 2r / 2r+1.
// Even rows also emit Zh bf16 (feeds ZZ^T).
__global__ __launch_bounds__(256) void k_dense(const float* __restrict__ A,     // [16384,128]
                                               const float* __restrict__ B,     // [128,64]
                                               const float* __restrict__ bias,  // [64]
                                               float* __restrict__ mu,
                                               float* __restrict__ logvar,
                                               ushort* __restrict__ Zh) {
    __shared__ float sA[16][68];
    __shared__ float sB[16][68];
    int tx = threadIdx.x, ty = threadIdx.y;
    int t = ty * 16 + tx;
    int row0 = blockIdx.x * 64;
    int am = t >> 2, ak = (t & 3) * 4;
    int bk = t >> 4, bn = (t & 15) * 4;
    float acc[4][4] = {};
    for (int k0 = 0; k0 < 128; k0 += 16) {
        float4 av = *(const float4*)&A[(size_t)(row0 + am) * 128 + k0 + ak];
        float4 bv = *(const float4*)&B[(size_t)(k0 + bk) * 64 + bn];
        sA[ak + 0][am] = av.x; sA[ak + 1][am] = av.y;
        sA[ak + 2][am] = av.z; sA[ak + 3][am] = av.w;
        *(float4*)&sB[bk][bn] = bv;
        __syncthreads();
#pragma unroll
        for (int k = 0; k < 16; k++) {
            float4 a4 = *(const float4*)&sA[k][ty * 4];
            float4 b4 = *(const float4*)&sB[k][tx * 4];
            float ar[4] = {a4.x, a4.y, a4.z, a4.w};
            float br[4] = {b4.x, b4.y, b4.z, b4.w};
#pragma unroll
            for (int a = 0; a < 4; a++)
#pragma unroll
                for (int b = 0; b < 4; b++) acc[a][b] += ar[a] * br[b];
        }
        __syncthreads();
    }
#pragma unroll
    for (int a = 0; a < 4; a++) {
        int vrow = row0 + ty * 4 + a;
        int col = tx * 4;
        float4 rv = make_float4(acc[a][0] + bias[col], acc[a][1] + bias[col + 1],
                                acc[a][2] + bias[col + 2], acc[a][3] + bias[col + 3]);
        int nr = vrow >> 1;
        if (vrow & 1) {
            *(float4*)&logvar[(size_t)nr * 64 + col] = rv;
        } else {
            *(float4*)&mu[(size_t)nr * 64 + col] = rv;
            ushort4 h = make_ushort4(f2bf(rv.x), f2bf(rv.y), f2bf(rv.z), f2bf(rv.w));
            *(ushort4*)&Zh[(size_t)nr * 64 + col] = h;
        }
    }
}

// ---------------- out6 = mu(8192x64) @ W(64x6) + b ----------------
__global__ __launch_bounds__(256) void k_out6(const float* __restrict__ Z,
                                              const float* __restrict__ W,
                                              const float* __restrict__ b,
                                              float* __restrict__ out) {
    __shared__ float sW[384];
    int t = threadIdx.x;
    for (int i = t; i < 384; i += 256) sW[i] = W[i];
    __syncthreads();
    int row = blockIdx.x * 256 + t;
    float acc[6];
#pragma unroll
    for (int j = 0; j < 6; j++) acc[j] = b[j];
    for (int k = 0; k < 64; k++) {
        float zv = Z[(size_t)row * 64 + k];
#pragma unroll
        for (int j = 0; j < 6; j++) acc[j] += zv * sW[k * 6 + j];
    }
#pragma unroll
    for (int j = 0; j < 6; j++) out[(size_t)row * 6 + j] = acc[j];
}

// ---------------- adj_rec = Z @ Z^T via bf16 MFMA ----------------
// Block = 256 thr = 4 waves, block tile 128x128, wave tile 64x64.
// Z is 8192x64 bf16 (1 MB, L2-resident) -> fragments loaded straight from global.
__global__ __launch_bounds__(256) void k_zzt_mfma(const ushort* __restrict__ Zh,
                                                  float* __restrict__ C) {
    int t = threadIdx.x;
    int lane = t & 63;
    int w = t >> 6;  // wave 0..3
    int I = blockIdx.y * 128 + (w >> 1) * 64;
    int J = blockIdx.x * 128 + (w & 1) * 64;
    int r = lane & 15;
    int koff = (lane >> 4) * 8;  // quad*8

    short8 a[4][2], b[4][2];
#pragma unroll
    for (int m = 0; m < 4; m++) {
#pragma unroll
        for (int kk = 0; kk < 2; kk++) {
            a[m][kk] = *(const short8*)(Zh + (size_t)(I + m * 16 + r) * 64 + kk * 32 + koff);
            b[m][kk] = *(const short8*)(Zh + (size_t)(J + m * 16 + r) * 64 + kk * 32 + koff);
        }
    }
    f32x4 acc[4][4];
#pragma unroll
    for (int m = 0; m < 4; m++)
#pragma unroll
        for (int n = 0; n < 4; n++) acc[m][n] = (f32x4){0.f, 0.f, 0.f, 0.f};

#pragma unroll
    for (int kk = 0; kk < 2; kk++)
#pragma unroll
        for (int m = 0; m < 4; m++)
#pragma unroll
            for (int n = 0; n < 4; n++)
                acc[m][n] = __builtin_amdgcn_mfma_f32_16x16x32_bf16(a[m][kk], b[n][kk],
                                                                    acc[m][n], 0, 0, 0);

    // C/D layout: col = lane&15, row = (lane>>4)*4 + reg   [m89-verified]
    int crow = (lane >> 4) * 4;
    int ccol = lane & 15;
#pragma unroll
    for (int m = 0; m < 4; m++)
#pragma unroll
        for (int rg = 0; rg < 4; rg++) {
            size_t row = (size_t)(I + m * 16 + crow + rg);
#pragma unroll
            for (int n = 0; n < 4; n++)
                C[row * 8192 + J + n * 16 + ccol] = acc[m][n][rg];
        }
}

extern "C" void kernel_launch(void* const* d_in, const int* in_sizes, int n_in,
                              void* d_out, int out_size, void* d_ws, size_t ws_size,
                              hipStream_t stream) {
    const float* x        = (const float*)d_in[0];
    const int*   adj_rows = (const int*)d_in[1];
    const int*   adj_cols = (const int*)d_in[2];
    const float* adj_vals = (const float*)d_in[3];
    const float* W1       = (const float*)d_in[4];
    const float* W2       = (const float*)d_in[5];
    const float* W3       = (const float*)d_in[6];
    const float* dense_W  = (const float*)d_in[7];
    const float* dense_b  = (const float*)d_in[8];
    const float* dense1_W = (const float*)d_in[9];
    const float* dense1_b = (const float*)d_in[10];

    // workspace layout (all chunks 16B-aligned)
    char* p = (char*)d_ws;
    int* counts  = (int*)p;    p += 8192 * 4;
    int* cursor  = (int*)p;    p += 8192 * 4;
    int* offs    = (int*)p;    p += 8224 * 4;                 // 8193 used, padded
    int* scol    = (int*)p;    p += (size_t)N_EDGES * 4;
    float* sval  = (float*)p;  p += (size_t)N_EDGES * 4;
    ushort* xh   = (ushort*)p; p += (size_t)8192 * 512 * 2;   // x bf16
    ushort* W1t  = (ushort*)p; p += (size_t)256 * 512 * 2;    // W1^T bf16
    ushort* W23t = (ushort*)p; p += (size_t)256 * 256 * 2;    // [W2|W3]^T bf16
    ushort* XW1h = (ushort*)p; p += (size_t)8192 * 256 * 2;   // x@W1 bf16
    ushort* Hidh = (ushort*)p; p += (size_t)8192 * 256 * 2;   // hidden1 bf16
    ushort* Tbh  = (ushort*)p; p += (size_t)8192 * 256 * 2;   // hidden1@[W2|W3] bf16
    float* Mb    = (float*)p;  p += (size_t)8192 * 256 * 4;   // spmm(T) fp32
    ushort* Zh   = (ushort*)p; p += (size_t)8192 * 64 * 2;    // mu bf16

    // output layout: adj_rec [8192x8192], out6 [8192x6], mu [8192x64], logvar [8192x64]
    float* out     = (float*)d_out;
    float* adj_rec = out;
    float* out6    = out + (size_t)8192 * 8192;
    float* mu      = out6 + (size_t)8192 * 6;
    float* logvar  = mu + (size_t)8192 * 64;

    hipMemsetAsync(counts, 0, 2 * 8192 * 4, stream);  // counts + cursor
    k_hist<<<N_EDGES / 256, 256, 0, stream>>>(adj_rows, counts);
    k_scan<<<1, 1024, 0, stream>>>(counts, offs);
    k_scatter<<<N_EDGES / 256, 256, 0, stream>>>(adj_rows, adj_cols, adj_vals, offs, cursor,
                                                 scol, sval);
    // bf16 conversions (independent of CSR build)
    k_conv_x<<<4096, 256, 0, stream>>>(x, xh);
    k_w1t<<<512, 256, 0, stream>>>(W1, W1t);
    k_w23t<<<256, 256, 0, stream>>>(W2, W3, W23t);

    // XW1 = x @ W1  (bf16 MFMA, M=8192 K=512 N=256)
    k_gemm_mfma<<<dim3(2, 64), 256, 0, stream>>>(xh, W1t, XW1h, 512, 256);
    // hidden1 = relu(spmm(XW1))  -> bf16
    k_spmm_h<<<8192, 256, 0, stream>>>(offs, scol, sval, XW1h, Hidh, nullptr, 1);
    // T = hidden1 @ [W2|W3]  (bf16 MFMA, K=256)
    k_gemm_mfma<<<dim3(2, 64), 256, 0, stream>>>(Hidh, W23t, Tbh, 256, 256);
    // M = spmm(T) -> fp32 [mu0 | logvar0]
    k_spmm_h<<<8192, 256, 0, stream>>>(offs, scol, sval, Tbh, nullptr, Mb, 0);
    // mu/logvar = Mb(interleaved view) @ dense_W + b ; Zh = bf16(mu) fused
    k_dense<<<256, dim3(16, 16), 0, stream>>>(Mb, dense_W, dense_b, mu, logvar, Zh);
    // out6 = mu @ dense1_W + dense1_b
    k_out6<<<32, 256, 0, stream>>>(mu, dense1_W, dense1_b, out6);
    // adj_rec = mu @ mu^T (bf16 MFMA, fp32 accumulate)
    k_zzt_mfma<<<dim3(64, 64), 256, 0, stream>>>(Zh, adj_rec);
}

// Round 3
// 418.813 us; speedup vs baseline: 1.1052x; 1.0160x over previous
//
#include <hip/hip_runtime.h>
#include <hip/hip_bf16.h>

#define N_NODES 8192
#define N_EDGES 262144
// F_IN=512, H1=256, H2=128 (x2 fused = 256), H3=64, OUT6=6

typedef __attribute__((ext_vector_type(8))) short short8;
typedef __attribute__((ext_vector_type(4))) float f32x4;

__device__ __forceinline__ unsigned short f2bf(float f) {
    unsigned int u = __float_as_uint(f);
    u = (u + 0x7fffu + ((u >> 16) & 1u)) >> 16;  // RNE
    return (unsigned short)u;
}
__device__ __forceinline__ float bf2f(unsigned short h) {
    return __uint_as_float((unsigned int)h << 16);
}

// ---------------- CSR build ----------------
__global__ void k_scan(const int* __restrict__ counts, int* __restrict__ offs) {
    __shared__ int part[1024];
    int t = threadIdx.x;
    int base = t * 8;
    int loc[8];
    int s = 0;
#pragma unroll
    for (int i = 0; i < 8; i++) { loc[i] = s; s += counts[base + i]; }
    part[t] = s;
    __syncthreads();
    for (int off = 1; off < 1024; off <<= 1) {
        int v = (t >= off) ? part[t - off] : 0;
        __syncthreads();
        part[t] += v;
        __syncthreads();
    }
    int prev = (t == 0) ? 0 : part[t - 1];
#pragma unroll
    for (int i = 0; i < 8; i++) offs[base + i] = prev + loc[i];
    if (t == 1023) offs[N_NODES] = part[1023];
}

__global__ void k_scatter(const int* __restrict__ rows, const int* __restrict__ colsIn,
                          const float* __restrict__ valsIn, const int* __restrict__ offs,
                          int* __restrict__ cursor, int* __restrict__ colsOut,
                          float* __restrict__ valsOut) {
    int e = blockIdx.x * 256 + threadIdx.x;
    if (e >= N_EDGES) return;
    int r = rows[e];
    int p = atomicAdd(&cursor[r], 1);
    int idx = offs[r] + p;
    colsOut[idx] = colsIn[e];
    valsOut[idx] = valsIn[e];
}

// ---------------- fused prep: hist + bf16 converts/transposes ----------------
// blocks [0,1024): hist; [1024,5120): x->bf16; [5120,5632): W1^T;
// [5632,5888): [W2|W3]^T; [5888,5920): dense_W^T
__global__ void k_prep(const int* __restrict__ rows, int* __restrict__ counts,
                       const float* __restrict__ x, ushort* __restrict__ xh,
                       const float* __restrict__ W1, ushort* __restrict__ W1t,
                       const float* __restrict__ W2, const float* __restrict__ W3,
                       ushort* __restrict__ W23t,
                       const float* __restrict__ dW, ushort* __restrict__ Wdt) {
    int b = blockIdx.x, t = threadIdx.x;
    if (b < 1024) {
        atomicAdd(&counts[rows[b * 256 + t]], 1);
    } else if (b < 5120) {
        int i = (b - 1024) * 256 + t;  // over 1048576 float4
        float4 v = ((const float4*)x)[i];
        ((ushort4*)xh)[i] = make_ushort4(f2bf(v.x), f2bf(v.y), f2bf(v.z), f2bf(v.w));
    } else if (b < 5632) {
        int i = (b - 5120) * 256 + t;  // over 131072, i = k*256+n
        int k = i >> 8, n = i & 255;
        W1t[n * 512 + k] = f2bf(W1[i]);
    } else if (b < 5888) {
        int i = (b - 5632) * 256 + t;  // over 65536, i = n*256+k
        int n = i >> 8, k = i & 255;
        float v = (n < 128) ? W2[k * 128 + n] : W3[k * 128 + (n - 128)];
        W23t[i] = f2bf(v);
    } else {
        int i = (b - 5888) * 256 + t;  // over 8192, i = j*128+k
        int j = i >> 7, k = i & 127;
        Wdt[i] = f2bf(dW[k * 64 + j]);
    }
}

// ---------------- bf16 MFMA GEMM: C[M,ldc] = A[M,K] @ Bt[N,K]^T, bf16 out ----------------
// block = 128 thr = 2 waves stacked on M; block tile 128x64; wave tile 64x64.
__global__ __launch_bounds__(128) void k_gemm_mfma(const ushort* __restrict__ A,
                                                   const ushort* __restrict__ Bt,
                                                   ushort* __restrict__ C,
                                                   int K, int ldc) {
    int t = threadIdx.x;
    int lane = t & 63;
    int w = t >> 6;
    int I = blockIdx.y * 128 + w * 64;
    int J = blockIdx.x * 64;
    int r = lane & 15;
    int koff = (lane >> 4) * 8;
    const ushort* Ab = A + (size_t)(I + r) * K + koff;
    const ushort* Bb = Bt + (size_t)(J + r) * K + koff;
    size_t rs = (size_t)16 * K;

    short8 a0[4], b0[4], a1[4], b1[4];
#pragma unroll
    for (int m = 0; m < 4; m++) {
        a0[m] = *(const short8*)(Ab + m * rs);
        b0[m] = *(const short8*)(Bb + m * rs);
    }
    f32x4 acc[4][4];
#pragma unroll
    for (int m = 0; m < 4; m++)
#pragma unroll
        for (int n = 0; n < 4; n++) acc[m][n] = (f32x4){0.f, 0.f, 0.f, 0.f};

    int nk = K >> 5;  // K=512 -> 16, K=256 -> 8 (even)
    for (int kt = 0; kt < nk; kt += 2) {
        int o1 = (kt + 1) << 5;
#pragma unroll
        for (int m = 0; m < 4; m++) {
            a1[m] = *(const short8*)(Ab + m * rs + o1);
            b1[m] = *(const short8*)(Bb + m * rs + o1);
        }
#pragma unroll
        for (int m = 0; m < 4; m++)
#pragma unroll
            for (int n = 0; n < 4; n++)
                acc[m][n] = __builtin_amdgcn_mfma_f32_16x16x32_bf16(a0[m], b0[n], acc[m][n], 0, 0, 0);
        if (kt + 2 < nk) {
            int o2 = (kt + 2) << 5;
#pragma unroll
            for (int m = 0; m < 4; m++) {
                a0[m] = *(const short8*)(Ab + m * rs + o2);
                b0[m] = *(const short8*)(Bb + m * rs + o2);
            }
        }
#pragma unroll
        for (int m = 0; m < 4; m++)
#pragma unroll
            for (int n = 0; n < 4; n++)
                acc[m][n] = __builtin_amdgcn_mfma_f32_16x16x32_bf16(a1[m], b1[n], acc[m][n], 0, 0, 0);
    }

    // C/D layout: col = lane&15, row = (lane>>4)*4 + reg   [m89-verified]
    int crow = (lane >> 4) * 4;
    int ccol = lane & 15;
#pragma unroll
    for (int m = 0; m < 4; m++)
#pragma unroll
        for (int rg = 0; rg < 4; rg++) {
            size_t row = (size_t)(I + m * 16 + crow + rg);
#pragma unroll
            for (int n = 0; n < 4; n++)
                C[row * ldc + J + n * 16 + ccol] = f2bf(acc[m][n][rg]);
        }
}

// ---------------- SpMM v2 (CSR), D=256 bf16: one row per WAVE ----------------
// 4 rows/block; lane owns 4 cols -> ushort4 gather = full 512B row per wave-instr.
// No LDS, no syncthreads; col/val 1-deep prefetch; fp32 accumulate.
__global__ __launch_bounds__(256) void k_spmm_v2(const int* __restrict__ offs,
                                                 const int* __restrict__ cols,
                                                 const float* __restrict__ vals,
                                                 const ushort* __restrict__ in,
                                                 ushort* __restrict__ out, int relu) {
    int w = threadIdx.x >> 6;
    int lane = threadIdx.x & 63;
    int row = blockIdx.x * 4 + w;
    int colo = lane * 4;
    int i = offs[row], e = offs[row + 1];
    float4 acc = make_float4(0.f, 0.f, 0.f, 0.f);
    int c = 0;
    float v = 0.f;
    if (i < e) { c = cols[i]; v = vals[i]; }
    while (i < e) {
        int cn = 0;
        float vn = 0.f;
        if (i + 1 < e) { cn = cols[i + 1]; vn = vals[i + 1]; }
        ushort4 u = *(const ushort4*)&in[(size_t)c * 256 + colo];
        acc.x += v * bf2f(u.x);
        acc.y += v * bf2f(u.y);
        acc.z += v * bf2f(u.z);
        acc.w += v * bf2f(u.w);
        c = cn; v = vn; ++i;
    }
    if (relu) {
        acc.x = fmaxf(acc.x, 0.f); acc.y = fmaxf(acc.y, 0.f);
        acc.z = fmaxf(acc.z, 0.f); acc.w = fmaxf(acc.w, 0.f);
    }
    *(ushort4*)&out[(size_t)row * 256 + colo] =
        make_ushort4(f2bf(acc.x), f2bf(acc.y), f2bf(acc.z), f2bf(acc.w));
}

// ---------------- dense via MFMA: view Mbh as [16384,128] bf16 ----------------
// view row vr = 2r+h -> Mb[r][h*128 + k] (contiguous). Even vr -> mu (+Zh bf16), odd -> logvar.
// Wdt = dense_W^T [64,128] bf16. Block = 256 thr = 4 waves stacked on M (256 rows/block).
__global__ __launch_bounds__(256) void k_dense_mfma(const ushort* __restrict__ A,
                                                    const ushort* __restrict__ Wdt,
                                                    const float* __restrict__ bias,
                                                    float* __restrict__ mu,
                                                    float* __restrict__ logvar,
                                                    ushort* __restrict__ Zh) {
    int t = threadIdx.x;
    int lane = t & 63;
    int w = t >> 6;
    int I = blockIdx.x * 256 + w * 64;
    int r = lane & 15;
    int koff = (lane >> 4) * 8;

    f32x4 acc[4][4];
#pragma unroll
    for (int m = 0; m < 4; m++)
#pragma unroll
        for (int n = 0; n < 4; n++) acc[m][n] = (f32x4){0.f, 0.f, 0.f, 0.f};

#pragma unroll
    for (int kk = 0; kk < 4; kk++) {
        short8 a[4], b[4];
#pragma unroll
        for (int m = 0; m < 4; m++)
            a[m] = *(const short8*)(A + (size_t)(I + m * 16 + r) * 128 + kk * 32 + koff);
#pragma unroll
        for (int n = 0; n < 4; n++)
            b[n] = *(const short8*)(Wdt + (size_t)(n * 16 + r) * 128 + kk * 32 + koff);
#pragma unroll
        for (int m = 0; m < 4; m++)
#pragma unroll
            for (int n = 0; n < 4; n++)
                acc[m][n] = __builtin_amdgcn_mfma_f32_16x16x32_bf16(a[m], b[n], acc[m][n], 0, 0, 0);
    }

    int crow = (lane >> 4) * 4;
    int ccol = lane & 15;
#pragma unroll
    for (int m = 0; m < 4; m++)
#pragma unroll
        for (int rg = 0; rg < 4; rg++) {
            int vrow = I + m * 16 + crow + rg;
            int nr = vrow >> 1;
#pragma unroll
            for (int n = 0; n < 4; n++) {
                int col = n * 16 + ccol;
                float val = acc[m][n][rg] + bias[col];
                if (vrow & 1) {
                    logvar[(size_t)nr * 64 + col] = val;
                } else {
                    mu[(size_t)nr * 64 + col] = val;
                    Zh[(size_t)nr * 64 + col] = f2bf(val);
                }
            }
        }
}

// ---------------- out6 = mu(8192x64) @ W(64x6) + b ----------------
__global__ __launch_bounds__(256) void k_out6(const float* __restrict__ Z,
                                              const float* __restrict__ W,
                                              const float* __restrict__ b,
                                              float* __restrict__ out) {
    __shared__ float sW[384];
    int t = threadIdx.x;
    for (int i = t; i < 384; i += 256) sW[i] = W[i];
    __syncthreads();
    int row = blockIdx.x * 256 + t;
    float acc[6];
#pragma unroll
    for (int j = 0; j < 6; j++) acc[j] = b[j];
    for (int k = 0; k < 64; k++) {
        float zv = Z[(size_t)row * 64 + k];
#pragma unroll
        for (int j = 0; j < 6; j++) acc[j] += zv * sW[k * 6 + j];
    }
#pragma unroll
    for (int j = 0; j < 6; j++) out[(size_t)row * 6 + j] = acc[j];
}

// ---------------- adj_rec = Z @ Z^T via bf16 MFMA ----------------
__global__ __launch_bounds__(256) void k_zzt_mfma(const ushort* __restrict__ Zh,
                                                  float* __restrict__ C) {
    int t = threadIdx.x;
    int lane = t & 63;
    int w = t >> 6;  // wave 0..3
    int I = blockIdx.y * 128 + (w >> 1) * 64;
    int J = blockIdx.x * 128 + (w & 1) * 64;
    int r = lane & 15;
    int koff = (lane >> 4) * 8;

    short8 a[4][2], b[4][2];
#pragma unroll
    for (int m = 0; m < 4; m++) {
#pragma unroll
        for (int kk = 0; kk < 2; kk++) {
            a[m][kk] = *(const short8*)(Zh + (size_t)(I + m * 16 + r) * 64 + kk * 32 + koff);
            b[m][kk] = *(const short8*)(Zh + (size_t)(J + m * 16 + r) * 64 + kk * 32 + koff);
        }
    }
    f32x4 acc[4][4];
#pragma unroll
    for (int m = 0; m < 4; m++)
#pragma unroll
        for (int n = 0; n < 4; n++) acc[m][n] = (f32x4){0.f, 0.f, 0.f, 0.f};

#pragma unroll
    for (int kk = 0; kk < 2; kk++)
#pragma unroll
        for (int m = 0; m < 4; m++)
#pragma unroll
            for (int n = 0; n < 4; n++)
                acc[m][n] = __builtin_amdgcn_mfma_f32_16x16x32_bf16(a[m][kk], b[n][kk],
                                                                    acc[m][n], 0, 0, 0);

    int crow = (lane >> 4) * 4;
    int ccol = lane & 15;
#pragma unroll
    for (int m = 0; m < 4; m++)
#pragma unroll
        for (int rg = 0; rg < 4; rg++) {
            size_t row = (size_t)(I + m * 16 + crow + rg);
#pragma unroll
            for (int n = 0; n < 4; n++)
                C[row * 8192 + J + n * 16 + ccol] = acc[m][n][rg];
        }
}

extern "C" void kernel_launch(void* const* d_in, const int* in_sizes, int n_in,
                              void* d_out, int out_size, void* d_ws, size_t ws_size,
                              hipStream_t stream) {
    const float* x        = (const float*)d_in[0];
    const int*   adj_rows = (const int*)d_in[1];
    const int*   adj_cols = (const int*)d_in[2];
    const float* adj_vals = (const float*)d_in[3];
    const float* W1       = (const float*)d_in[4];
    const float* W2       = (const float*)d_in[5];
    const float* W3       = (const float*)d_in[6];
    const float* dense_W  = (const float*)d_in[7];
    const float* dense_b  = (const float*)d_in[8];
    const float* dense1_W = (const float*)d_in[9];
    const float* dense1_b = (const float*)d_in[10];

    // workspace layout (all chunks 16B-aligned)
    char* p = (char*)d_ws;
    int* counts  = (int*)p;    p += 8192 * 4;
    int* cursor  = (int*)p;    p += 8192 * 4;
    int* offs    = (int*)p;    p += 8224 * 4;                 // 8193 used, padded
    int* scol    = (int*)p;    p += (size_t)N_EDGES * 4;
    float* sval  = (float*)p;  p += (size_t)N_EDGES * 4;
    ushort* xh   = (ushort*)p; p += (size_t)8192 * 512 * 2;   // x bf16
    ushort* W1t  = (ushort*)p; p += (size_t)256 * 512 * 2;    // W1^T bf16
    ushort* W23t = (ushort*)p; p += (size_t)256 * 256 * 2;    // [W2|W3]^T bf16
    ushort* Wdt  = (ushort*)p; p += (size_t)64 * 128 * 2;     // dense_W^T bf16
    ushort* XW1h = (ushort*)p; p += (size_t)8192 * 256 * 2;   // x@W1 bf16
    ushort* Hidh = (ushort*)p; p += (size_t)8192 * 256 * 2;   // hidden1 bf16
    ushort* Tbh  = (ushort*)p; p += (size_t)8192 * 256 * 2;   // hidden1@[W2|W3] bf16
    ushort* Mbh  = (ushort*)p; p += (size_t)8192 * 256 * 2;   // spmm(T) bf16
    ushort* Zh   = (ushort*)p; p += (size_t)8192 * 64 * 2;    // mu bf16

    // output layout: adj_rec [8192x8192], out6 [8192x6], mu [8192x64], logvar [8192x64]
    float* out     = (float*)d_out;
    float* adj_rec = out;
    float* out6    = out + (size_t)8192 * 8192;
    float* mu      = out6 + (size_t)8192 * 6;
    float* logvar  = mu + (size_t)8192 * 64;

    hipMemsetAsync(counts, 0, 2 * 8192 * 4, stream);  // counts + cursor
    // hist + all bf16 converts/transposes in one launch
    k_prep<<<5920, 256, 0, stream>>>(adj_rows, counts, x, xh, W1, W1t, W2, W3, W23t,
                                     dense_W, Wdt);
    k_scan<<<1, 1024, 0, stream>>>(counts, offs);
    k_scatter<<<N_EDGES / 256, 256, 0, stream>>>(adj_rows, adj_cols, adj_vals, offs, cursor,
                                                 scol, sval);

    // XW1 = x @ W1  (bf16 MFMA, M=8192 K=512 N=256) — 256 blocks, all CUs
    k_gemm_mfma<<<dim3(4, 64), 128, 0, stream>>>(xh, W1t, XW1h, 512, 256);
    // hidden1 = relu(spmm(XW1))  -> bf16
    k_spmm_v2<<<2048, 256, 0, stream>>>(offs, scol, sval, XW1h, Hidh, 1);
    // T = hidden1 @ [W2|W3]  (bf16 MFMA, K=256)
    k_gemm_mfma<<<dim3(4, 64), 128, 0, stream>>>(Hidh, W23t, Tbh, 256, 256);
    // M = spmm(T) -> bf16 [mu0 | logvar0]
    k_spmm_v2<<<2048, 256, 0, stream>>>(offs, scol, sval, Tbh, Mbh, 0);
    // mu/logvar = Mb(interleaved [16384,128] view) @ dense_W + b ; Zh fused
    k_dense_mfma<<<64, 256, 0, stream>>>(Mbh, Wdt, dense_b, mu, logvar, Zh);
    // out6 = mu @ dense1_W + dense1_b
    k_out6<<<32, 256, 0, stream>>>(mu, dense1_W, dense1_b, out6);
    // adj_rec = mu @ mu^T (bf16 MFMA, fp32 accumulate)
    k_zzt_mfma<<<dim3(64, 64), 256, 0, stream>>>(Zh, adj_rec);
}